// Round 1
// baseline (3398.647 us; speedup 1.0000x reference)
//
#include <hip/hip_runtime.h>
#include <cstddef>

#define HH 256
#define WW 256
#define NB 4
#define NFC 64
#define EMBC 512

constexpr int TH = 8, TW = 32;

// ---------------------------------------------------------------------------
// Modulated-weight computation: one block per (b, co), 64 threads (ci).
// wgt[b,co,ci,k] = demod[b,co] * scale * base_w[co,ci,k] * style[b,ci]
// style[b,ci] = emb[b,:] . mw[ci,:] + mb[ci]
// demod[b,co] = rsqrt(sum_{ci,k} wgt_pre^2 + 1e-8)
// ---------------------------------------------------------------------------
__global__ void modw_kernel(const float* __restrict__ emb, const float* __restrict__ mw,
                            const float* __restrict__ mb, const float* __restrict__ bw,
                            float* __restrict__ outw)
{
    const int co = blockIdx.x, b = blockIdx.y;
    const int ci = threadIdx.x;

    const float* e = emb + (size_t)b * EMBC;
    const float* m = mw + (size_t)ci * EMBC;
    float s = mb[ci];
    for (int k = 0; k < EMBC; k += 4) {
        float4 ev = *(const float4*)(e + k);
        float4 mv = *(const float4*)(m + k);
        s += ev.x * mv.x + ev.y * mv.y + ev.z * mv.z + ev.w * mv.w;
    }

    float w[9];
    float ss = 0.f;
    const float* src = bw + ((size_t)co * NFC + ci) * 9;
#pragma unroll
    for (int k = 0; k < 9; ++k) {
        float v = (1.0f / 24.0f) * src[k] * s;   // scale = 1/sqrt(64*9)
        w[k] = v;
        ss += v * v;
    }
#pragma unroll
    for (int off = 32; off; off >>= 1) ss += __shfl_xor(ss, off);
    float demod = rsqrtf(ss + 1e-8f);

    float* o = outw + (((size_t)b * NFC + co) * NFC + ci) * 9;
#pragma unroll
    for (int k = 0; k < 9; ++k) o[k] = w[k] * demod;
}

// ---------------------------------------------------------------------------
// Direct 3x3 conv, pad=1. Block: 256 threads, tile 32(w) x 8(h), up to 64 co.
// Each thread: 8 contiguous pixels along w, CPT output channels.
// CIN input channels staged through LDS in chunks of CHUNK.
// ---------------------------------------------------------------------------
template <int CIN, int CHUNK, int CPT, bool PERB, bool BIAS, bool LRELU, bool NOISE>
__global__ __launch_bounds__(256) void conv3x3(
    const float* __restrict__ in, const float* __restrict__ wgt,
    const float* __restrict__ bias, const float* __restrict__ noise,
    const float* __restrict__ wnp, float* __restrict__ out, int Cout)
{
    constexpr int COSLOT = 8 * CPT;
    __shared__ float xs[CHUNK][10][36];          // rows h0-1..h0+8, cols w0-1..w0+32 (+pad)
    __shared__ float ws[COSLOT][CHUNK][12];      // 9 weights + pad for float4 reads

    const int tid = threadIdx.x;
    const int pxg = tid & 31, cog = tid >> 5;
    const int r = pxg >> 2;                      // row within tile (0..7)
    const int p0 = (pxg & 3) * 8;                // pixel strip start (0,8,16,24)
    const int w0 = blockIdx.x * TW, h0 = blockIdx.y * TH, b = blockIdx.z;

    float acc[CPT][8];
#pragma unroll
    for (int c = 0; c < CPT; ++c)
#pragma unroll
        for (int p = 0; p < 8; ++p) acc[c][p] = 0.f;

    for (int ci0 = 0; ci0 < CIN; ci0 += CHUNK) {
        if (ci0) __syncthreads();
        // --- stage x tile: CHUNK planes of 10x36 (zero-padded borders) ---
        constexpr int XEL = CHUNK * 360;
        for (int idx = tid; idx < XEL; idx += 256) {
            int ci = idx / 360, rem = idx - ci * 360;
            int row = rem / 36, col = rem - row * 36;
            int gh = h0 + row - 1, gw = w0 + col - 1;
            float v = 0.f;
            if (col < 34 && (unsigned)gh < HH && (unsigned)gw < WW)
                v = in[(((size_t)b * CIN + ci0 + ci) * HH + gh) * WW + gw];
            xs[ci][row][col] = v;
        }
        // --- stage weights: COSLOT co x CHUNK ci x 9 ---
        constexpr int WEL = COSLOT * CHUNK * 9;
        for (int idx = tid; idx < WEL; idx += 256) {
            int co = idx / (CHUNK * 9), rem = idx - co * (CHUNK * 9);
            int ci = rem / 9, k = rem - ci * 9;
            float v = 0.f;
            if (co < Cout) {
                const float* src = PERB
                    ? wgt + (((size_t)b * NFC + co) * CIN + ci0 + ci) * 9 + k
                    : wgt + ((size_t)co * CIN + ci0 + ci) * 9 + k;
                v = *src;
            }
            ws[co][ci][k] = v;
        }
        __syncthreads();

        for (int ci = 0; ci < CHUNK; ++ci) {
            float xr0[10], xr1[10], xr2[10];
            {
                const float* s0 = &xs[ci][r][p0];
                const float* s1 = &xs[ci][r + 1][p0];
                const float* s2 = &xs[ci][r + 2][p0];
                float4 a; float2 t;
                a = *(const float4*)(s0);     xr0[0]=a.x; xr0[1]=a.y; xr0[2]=a.z; xr0[3]=a.w;
                a = *(const float4*)(s0 + 4); xr0[4]=a.x; xr0[5]=a.y; xr0[6]=a.z; xr0[7]=a.w;
                t = *(const float2*)(s0 + 8); xr0[8]=t.x; xr0[9]=t.y;
                a = *(const float4*)(s1);     xr1[0]=a.x; xr1[1]=a.y; xr1[2]=a.z; xr1[3]=a.w;
                a = *(const float4*)(s1 + 4); xr1[4]=a.x; xr1[5]=a.y; xr1[6]=a.z; xr1[7]=a.w;
                t = *(const float2*)(s1 + 8); xr1[8]=t.x; xr1[9]=t.y;
                a = *(const float4*)(s2);     xr2[0]=a.x; xr2[1]=a.y; xr2[2]=a.z; xr2[3]=a.w;
                a = *(const float4*)(s2 + 4); xr2[4]=a.x; xr2[5]=a.y; xr2[6]=a.z; xr2[7]=a.w;
                t = *(const float2*)(s2 + 8); xr2[8]=t.x; xr2[9]=t.y;
            }
#pragma unroll
            for (int c = 0; c < CPT; ++c) {
                const int co = cog * CPT + c;
                const float* wp = &ws[co][ci][0];
                float4 wa = *(const float4*)wp;
                float4 wb = *(const float4*)(wp + 4);
                float w8 = wp[8];
#pragma unroll
                for (int p = 0; p < 8; ++p) {
                    float s = acc[c][p];
                    s += wa.x * xr0[p];     s += wa.y * xr0[p + 1]; s += wa.z * xr0[p + 2];
                    s += wa.w * xr1[p];     s += wb.x * xr1[p + 1]; s += wb.y * xr1[p + 2];
                    s += wb.z * xr2[p];     s += wb.w * xr2[p + 1]; s += w8  * xr2[p + 2];
                    acc[c][p] = s;
                }
            }
        }
    }

    // --- epilogue ---
    const int h = h0 + r, wbv = w0 + p0;
    float wn = 0.f;
    float nz[8];
    if (NOISE) {
        wn = wnp[0];
        const float* np_ = noise + ((size_t)b * HH + h) * WW + wbv;
        float4 a = *(const float4*)np_;       nz[0]=a.x; nz[1]=a.y; nz[2]=a.z; nz[3]=a.w;
        a = *(const float4*)(np_ + 4);        nz[4]=a.x; nz[5]=a.y; nz[6]=a.z; nz[7]=a.w;
    }
#pragma unroll
    for (int c = 0; c < CPT; ++c) {
        const int co = cog * CPT + c;
        if (co < Cout) {
            float bv = BIAS ? bias[co] : 0.f;
            float tmp[8];
#pragma unroll
            for (int p = 0; p < 8; ++p) {
                float v = acc[c][p] + bv;
                if (NOISE) v += wn * nz[p];
                if (LRELU) v = v >= 0.f ? v : 0.1f * v;
                tmp[p] = v;
            }
            float* op = out + (((size_t)b * Cout + co) * HH + h) * WW + wbv;
            *(float4*)op       = make_float4(tmp[0], tmp[1], tmp[2], tmp[3]);
            *(float4*)(op + 4) = make_float4(tmp[4], tmp[5], tmp[6], tmp[7]);
        }
    }
}

// ---------------------------------------------------------------------------
extern "C" void kernel_launch(void* const* d_in, const int* in_sizes, int n_in,
                              void* d_out, int out_size, void* d_ws, size_t ws_size,
                              hipStream_t stream)
{
    auto F = [&](int i) { return (const float*)d_in[i]; };
    const float* x       = F(0);
    const float* emb     = F(1);
    const float* noise[3] = {F(2), F(3), F(4)};
    const float* w_first = F(5);  const float* b_first = F(6);
    const float* w_hr[5] = {F(7), F(9), F(11), F(13), F(15)};
    const float* b_hr[5] = {F(8), F(10), F(12), F(14), F(16)};
    const float* w_last  = F(17); const float* b_last = F(18);
    const float *m_mw[3], *m_mb[3], *m_w[3], *m_cw[3], *m_cb[3], *m_wn[3];
    for (int i = 0; i < 3; ++i) {
        int o = 19 + 6 * i;
        m_mw[i] = F(o); m_mb[i] = F(o + 1); m_w[i] = F(o + 2);
        m_cw[i] = F(o + 3); m_cb[i] = F(o + 4); m_wn[i] = F(o + 5);
    }

    const size_t ACT = (size_t)NB * NFC * HH * WW;       // 16.78M floats
    const size_t MODW = (size_t)NB * NFC * NFC * 9;      // 147456 floats
    float* act0 = (float*)d_ws;
    float* act1 = act0 + ACT;
    float* mwb[3];
    mwb[0] = act1 + ACT;
    mwb[1] = mwb[0] + MODW;
    mwb[2] = mwb[1] + MODW;

    // modulated weights (tiny)
    dim3 mg(NFC, NB);
    for (int i = 0; i < 3; ++i)
        modw_kernel<<<mg, NFC, 0, stream>>>(emb, m_mw[i], m_mb[i], m_w[i], mwb[i]);

    dim3 grid(WW / TW, HH / TH, NB), blk(256);

    // first: 3->64, bias+lrelu
    conv3x3<3, 3, 8, false, true, true, false>
        <<<grid, blk, 0, stream>>>(x, w_first, b_first, nullptr, nullptr, act0, NFC);

    float* cur = act0;
    float* nxt = act1;
    for (int i = 0; i < 3; ++i) {
        // modulated grouped conv (per-batch weights), +wn*noise, no bias/lrelu
        conv3x3<64, 8, 8, true, false, false, true>
            <<<grid, blk, 0, stream>>>(cur, mwb[i], nullptr, noise[i], m_wn[i], nxt, NFC);
        { float* t = cur; cur = nxt; nxt = t; }
        // conv_last of mod block: bias + lrelu
        conv3x3<64, 8, 8, false, true, true, false>
            <<<grid, blk, 0, stream>>>(cur, m_cw[i], m_cb[i], nullptr, nullptr, nxt, NFC);
        { float* t = cur; cur = nxt; nxt = t; }
        // hr conv (hr1/hr2/hr3): bias, no lrelu
        conv3x3<64, 8, 8, false, true, false, false>
            <<<grid, blk, 0, stream>>>(cur, w_hr[i], b_hr[i], nullptr, nullptr, nxt, NFC);
        { float* t = cur; cur = nxt; nxt = t; }
    }
    // hr4, hr5
    conv3x3<64, 8, 8, false, true, false, false>
        <<<grid, blk, 0, stream>>>(cur, w_hr[3], b_hr[3], nullptr, nullptr, nxt, NFC);
    { float* t = cur; cur = nxt; nxt = t; }
    conv3x3<64, 8, 8, false, true, false, false>
        <<<grid, blk, 0, stream>>>(cur, w_hr[4], b_hr[4], nullptr, nullptr, nxt, NFC);
    { float* t = cur; cur = nxt; nxt = t; }

    // last: 64->3, bias, no lrelu -> d_out
    conv3x3<64, 8, 1, false, true, false, false>
        <<<grid, blk, 0, stream>>>(cur, w_last, b_last, nullptr, nullptr, (float*)d_out, 3);
}

// Round 2
// 966.998 us; speedup vs baseline: 3.5146x; 3.5146x over previous
//
#include <hip/hip_runtime.h>
#include <cstddef>

#define HH 256
#define WW 256
#define NB 4
#define NFC 64
#define EMBC 512

typedef short s16x8 __attribute__((ext_vector_type(8)));
typedef float f32x4 __attribute__((ext_vector_type(4)));

static __device__ __forceinline__ unsigned short f2b(float f) {
    // round-to-nearest-even f32 -> bf16
    unsigned int u = __float_as_uint(f);
    u += 0x7FFFu + ((u >> 16) & 1u);
    return (unsigned short)(u >> 16);
}
static __device__ __forceinline__ float b2f(unsigned short u) {
    return __uint_as_float(((unsigned int)u) << 16);
}

// ---------------------------------------------------------------------------
// Modulated weights -> bf16 transposed [b][tap][co][ci]. Block (co,b), 64 thr (ci).
// ---------------------------------------------------------------------------
__global__ void modw_kernel(const float* __restrict__ emb, const float* __restrict__ mw,
                            const float* __restrict__ mb, const float* __restrict__ bw,
                            unsigned short* __restrict__ outw)
{
    const int co = blockIdx.x, b = blockIdx.y;
    const int ci = threadIdx.x;

    const float* e = emb + (size_t)b * EMBC;
    const float* m = mw + (size_t)ci * EMBC;
    float s = mb[ci];
    for (int k = 0; k < EMBC; k += 4) {
        float4 ev = *(const float4*)(e + k);
        float4 mv = *(const float4*)(m + k);
        s += ev.x * mv.x + ev.y * mv.y + ev.z * mv.z + ev.w * mv.w;
    }

    float w[9];
    float ss = 0.f;
    const float* src = bw + ((size_t)co * NFC + ci) * 9;
#pragma unroll
    for (int k = 0; k < 9; ++k) {
        float v = (1.0f / 24.0f) * src[k] * s;   // scale = 1/sqrt(64*9)
        w[k] = v;
        ss += v * v;
    }
#pragma unroll
    for (int off = 32; off; off >>= 1) ss += __shfl_xor(ss, off);
    float demod = rsqrtf(ss + 1e-8f);

#pragma unroll
    for (int k = 0; k < 9; ++k)
        outw[(((size_t)b * 9 + k) * NFC + co) * NFC + ci] = f2b(w[k] * demod);
}

// ---------------------------------------------------------------------------
// Fixed-weight transform: w[co][ci][3][3] f32 -> wt[tap][COP][64] bf16 (co>=Cout -> 0)
// ---------------------------------------------------------------------------
__global__ void fixw_kernel(const float* __restrict__ w, unsigned short* __restrict__ wt,
                            int Cout, int COP)
{
    int idx = blockIdx.x * 256 + threadIdx.x;
    int total = 9 * COP * NFC;
    if (idx >= total) return;
    int k = idx / (COP * NFC);
    int rem = idx - k * (COP * NFC);
    int co = rem / NFC, ci = rem - co * NFC;
    float v = (co < Cout) ? w[((size_t)co * NFC + ci) * 9 + k] : 0.f;
    wt[idx] = f2b(v);
}

// ---------------------------------------------------------------------------
// Layer 0: 3->64 direct conv, fp32 NCHW in -> bf16 NHWC out, bias+lrelu.
// Block: 16x16 pixel tile, one thread per pixel computing all 64 co.
// ---------------------------------------------------------------------------
__global__ __launch_bounds__(256) void conv_first(
    const float* __restrict__ x, const float* __restrict__ w,
    const float* __restrict__ bias, unsigned short* __restrict__ out)
{
    __shared__ float wf[64 * 27];
    __shared__ float bs[64];
    const int tid = threadIdx.x;
    for (int i = tid; i < 64 * 27; i += 256) wf[i] = w[i];
    if (tid < 64) bs[tid] = bias[tid];
    __syncthreads();

    const int b = blockIdx.z;
    const int h = blockIdx.y * 16 + (tid >> 4);
    const int wcol = blockIdx.x * 16 + (tid & 15);

    float xi[27];
#pragma unroll
    for (int ci = 0; ci < 3; ++ci)
#pragma unroll
        for (int kh = 0; kh < 3; ++kh)
#pragma unroll
            for (int kw = 0; kw < 3; ++kw) {
                int gh = h + kh - 1, gw = wcol + kw - 1;
                float v = 0.f;
                if ((unsigned)gh < HH && (unsigned)gw < WW)
                    v = x[(((size_t)b * 3 + ci) * HH + gh) * WW + gw];
                xi[ci * 9 + kh * 3 + kw] = v;
            }

    unsigned short* op = out + (((size_t)b * HH + h) * WW + wcol) * NFC;
    for (int co0 = 0; co0 < 64; co0 += 8) {
        unsigned short pk[8];
#pragma unroll
        for (int c = 0; c < 8; ++c) {
            const float* wp = &wf[(co0 + c) * 27];
            float s = bs[co0 + c];
#pragma unroll
            for (int t = 0; t < 27; ++t) s += wp[t] * xi[t];
            s = s >= 0.f ? s : 0.1f * s;
            pk[c] = f2b(s);
        }
        *(uint4*)(op + co0) = *(uint4*)pk;
    }
}

// ---------------------------------------------------------------------------
// Main MFMA conv: bf16 NHWC in [B][256][256][64] -> out.
// Implicit GEMM: M=co, N=16x16 px tile, K=576 (9 taps x 64 ci).
// Block 256 thr = 4 waves; wave computes co=COP x 4 rows x 16 w.
// LDS: 18x18 halo tile, ci innermost, XOR-swizzled 16B slots.
// ---------------------------------------------------------------------------
template <int MFRAGS, bool PERB, bool BIAS, bool LRELU, bool NOISE, bool OUTF32>
__global__ __launch_bounds__(256, 3) void mconv(
    const unsigned short* __restrict__ in, const unsigned short* __restrict__ wt,
    const float* __restrict__ bias, const float* __restrict__ noise,
    const float* __restrict__ wnp, void* __restrict__ outv)
{
    constexpr int COP = MFRAGS * 16;
    __shared__ uint4 xs[18 * 18 * 8];   // 41472 B

    const int tid = threadIdx.x;
    const int b = blockIdx.z, h0 = blockIdx.y * 16, w0 = blockIdx.x * 16;

    // --- stage halo tile (zero-padded) with slot swizzle ---
    for (int idx = tid; idx < 18 * 18 * 8; idx += 256) {
        int row = idx / 144, rem = idx - row * 144;
        int w = rem >> 3, slot = rem & 7;
        int gh = h0 + row - 1, gw = w0 + w - 1;
        uint4 v = make_uint4(0, 0, 0, 0);
        if ((unsigned)gh < HH && (unsigned)gw < WW)
            v = *(const uint4*)(in + (((size_t)b * HH + gh) * WW + gw) * NFC + slot * 8);
        xs[(row * 18 + w) * 8 + (slot ^ (w & 7))] = v;
    }
    __syncthreads();

    const int lane = tid & 63, wid = tid >> 6;
    const int m16 = lane & 15, kg = lane >> 4;

    const unsigned short* wbase = PERB ? wt + (size_t)b * 9 * COP * NFC : wt;

    f32x4 acc[MFRAGS][4];
#pragma unroll
    for (int mf = 0; mf < MFRAGS; ++mf)
#pragma unroll
        for (int r = 0; r < 4; ++r) acc[mf][r] = (f32x4)(0.f);

#pragma unroll
    for (int kh = 0; kh < 3; ++kh)
#pragma unroll
        for (int kw = 0; kw < 3; ++kw) {
            const int tap = kh * 3 + kw;
            const int lw = m16 + kw;
#pragma unroll
            for (int half = 0; half < 2; ++half) {
                s16x8 a[MFRAGS];
                const unsigned short* wp = wbase + ((size_t)tap * COP + m16) * NFC + half * 32 + kg * 8;
#pragma unroll
                for (int mf = 0; mf < MFRAGS; ++mf)
                    a[mf] = *(const s16x8*)(wp + mf * 16 * NFC);
                const int slot = (half * 4 + kg) ^ (lw & 7);
#pragma unroll
                for (int r = 0; r < 4; ++r) {
                    const int lrow = wid * 4 + r + kh;
                    s16x8 bf = *(const s16x8*)&xs[(lrow * 18 + lw) * 8 + slot];
#pragma unroll
                    for (int mf = 0; mf < MFRAGS; ++mf)
                        acc[mf][r] = __builtin_amdgcn_mfma_f32_16x16x32_bf16(
                            a[mf], bf, acc[mf][r], 0, 0, 0);
                }
            }
        }

    // --- epilogue ---
    const int wcol = w0 + m16;
    const float wn = NOISE ? wnp[0] : 0.f;
#pragma unroll
    for (int r = 0; r < 4; ++r) {
        const int h = h0 + wid * 4 + r;
        float nz = 0.f;
        if (NOISE) nz = noise[((size_t)b * HH + h) * WW + wcol];
#pragma unroll
        for (int mf = 0; mf < MFRAGS; ++mf) {
            const int cob = mf * 16 + kg * 4;
            f32x4 v = acc[mf][r];
            float4 bv = make_float4(0.f, 0.f, 0.f, 0.f);
            if (BIAS) bv = *(const float4*)(bias + cob);
            float o[4];
#pragma unroll
            for (int e = 0; e < 4; ++e) {
                float t = v[e] + (BIAS ? (&bv.x)[e] : 0.f);
                if (NOISE) t += wn * nz;
                if (LRELU) t = t >= 0.f ? t : 0.1f * t;
                o[e] = t;
            }
            if (OUTF32) {
                float* of = (float*)outv;
#pragma unroll
                for (int e = 0; e < 4; ++e) {
                    int co = cob + e;
                    if (co < 3)
                        of[(((size_t)b * 3 + co) * HH + h) * WW + wcol] = o[e];
                }
            } else {
                unsigned short pk[4];
#pragma unroll
                for (int e = 0; e < 4; ++e) pk[e] = f2b(o[e]);
                unsigned short* ob = (unsigned short*)outv;
                *(ushort4*)(ob + (((size_t)b * HH + h) * WW + wcol) * NFC + cob) = *(ushort4*)pk;
            }
        }
    }
}

// ---------------------------------------------------------------------------
extern "C" void kernel_launch(void* const* d_in, const int* in_sizes, int n_in,
                              void* d_out, int out_size, void* d_ws, size_t ws_size,
                              hipStream_t stream)
{
    auto F = [&](int i) { return (const float*)d_in[i]; };
    const float* x       = F(0);
    const float* emb     = F(1);
    const float* noise[3] = {F(2), F(3), F(4)};
    const float* w_first = F(5);  const float* b_first = F(6);
    const float* w_hr[5] = {F(7), F(9), F(11), F(13), F(15)};
    const float* b_hr[5] = {F(8), F(10), F(12), F(14), F(16)};
    const float* w_last  = F(17); const float* b_last = F(18);
    const float *m_mw[3], *m_mb[3], *m_w[3], *m_cw[3], *m_cb[3], *m_wn[3];
    for (int i = 0; i < 3; ++i) {
        int o = 19 + 6 * i;
        m_mw[i] = F(o); m_mb[i] = F(o + 1); m_w[i] = F(o + 2);
        m_cw[i] = F(o + 3); m_cb[i] = F(o + 4); m_wn[i] = F(o + 5);
    }

    // workspace layout (bf16 = unsigned short)
    const size_t ACT = (size_t)NB * HH * WW * NFC;      // 16.78M elems
    unsigned short* act0 = (unsigned short*)d_ws;
    unsigned short* act1 = act0 + ACT;
    unsigned short* p = act1 + ACT;
    unsigned short* wmod[3];
    for (int i = 0; i < 3; ++i) { wmod[i] = p; p += (size_t)NB * 9 * NFC * NFC; }
    unsigned short* wfix[8];                            // cl0,cl1,cl2,hr1..hr5
    for (int i = 0; i < 8; ++i) { wfix[i] = p; p += (size_t)9 * NFC * NFC; }
    unsigned short* wlast = p;                          // 9*16*64

    // --- weight preparation (tiny) ---
    dim3 mg(NFC, NB);
    for (int i = 0; i < 3; ++i)
        modw_kernel<<<mg, NFC, 0, stream>>>(emb, m_mw[i], m_mb[i], m_w[i], wmod[i]);
    for (int i = 0; i < 3; ++i)
        fixw_kernel<<<(9 * 64 * 64 + 255) / 256, 256, 0, stream>>>(m_cw[i], wfix[i], 64, 64);
    for (int i = 0; i < 5; ++i)
        fixw_kernel<<<(9 * 64 * 64 + 255) / 256, 256, 0, stream>>>(w_hr[i], wfix[3 + i], 64, 64);
    fixw_kernel<<<(9 * 16 * 64 + 255) / 256, 256, 0, stream>>>(w_last, wlast, 3, 16);

    dim3 grid(WW / 16, HH / 16, NB), blk(256);

    // layer 0: 3->64 bias+lrelu
    conv_first<<<grid, blk, 0, stream>>>(x, w_first, b_first, act0);

    unsigned short* cur = act0;
    unsigned short* nxt = act1;
    auto swap = [&]() { unsigned short* t = cur; cur = nxt; nxt = t; };

    for (int i = 0; i < 3; ++i) {
        // modulated grouped conv: per-batch weights, +wn*noise
        mconv<4, true, false, false, true, false>
            <<<grid, blk, 0, stream>>>(cur, wmod[i], nullptr, noise[i], m_wn[i], nxt);
        swap();
        // conv_last: bias + lrelu
        mconv<4, false, true, true, false, false>
            <<<grid, blk, 0, stream>>>(cur, wfix[i], m_cb[i], nullptr, nullptr, nxt);
        swap();
        // hr1/hr2/hr3: bias
        mconv<4, false, true, false, false, false>
            <<<grid, blk, 0, stream>>>(cur, wfix[3 + i], b_hr[i], nullptr, nullptr, nxt);
        swap();
    }
    // hr4, hr5
    mconv<4, false, true, false, false, false>
        <<<grid, blk, 0, stream>>>(cur, wfix[6], b_hr[3], nullptr, nullptr, nxt);
    swap();
    mconv<4, false, true, false, false, false>
        <<<grid, blk, 0, stream>>>(cur, wfix[7], b_hr[4], nullptr, nullptr, nxt);
    swap();
    // last: 64->3, fp32 NCHW -> d_out
    mconv<1, false, true, false, false, true>
        <<<grid, blk, 0, stream>>>(cur, wlast, b_last, nullptr, nullptr, d_out);
}